// Round 5
// baseline (359.129 us; speedup 1.0000x reference)
//
#include <hip/hip_runtime.h>
#include <math.h>

#define NCLS 19
#define DIM  128
#define CD   (NCLS * DIM)   // 2432 floats
#define WPB  8              // waves per block (512 threads)
#define NBLK 256            // == CU count; 1 block/CU -> all co-resident
#define NTHR 512
#define NWAVES (NBLK * WPB) // 2048 waves grid-wide
#define NRP  32             // pairs held in registers per wave (128 VGPRs)
#define NLP  16             // pairs held in LDS per wave (16 KB/wave)
#define PPW  64             // pairs per wave in the exact-fit case

typedef float f32x4 __attribute__((ext_vector_type(4)));

// Nontemporal load for held data (never re-read from global) -> no L3 alloc.
__device__ __forceinline__ float4 ntload4(const float4* p) {
    f32x4 r = __builtin_nontemporal_load((const f32x4*)p);
    return make_float4(r.x, r.y, r.z, r.w);
}

// 32-lane-group sum via DPP on the VALU pipe. Valid in lanes 31 and 63.
template <int CTRL, int RMASK>
__device__ __forceinline__ float dpp_add(float x) {
    int t = __builtin_amdgcn_update_dpp(0, __builtin_bit_cast(int, x),
                                        CTRL, RMASK, 0xf, true);
    return x + __builtin_bit_cast(float, t);
}
__device__ __forceinline__ float reduce32_dpp(float x) {
    x = dpp_add<0x111, 0xf>(x);   // row_shr:1
    x = dpp_add<0x112, 0xf>(x);   // row_shr:2
    x = dpp_add<0x114, 0xf>(x);   // row_shr:4
    x = dpp_add<0x118, 0xf>(x);   // row_shr:8
    x = dpp_add<0x142, 0xa>(x);   // row_bcast15 -> lanes 31/63 hold 32-sums
    return x;
}

// Fire-and-forget accumulate into the block-shared SWIZZLED table.
// Table layout within a class row: dim d lives at word (d>>2) + (d&3)*32, so
// the 4 ds_add_f32 ops of a half-wave hit bank l31 (2 lanes/bank = free).
__device__ __forceinline__ void acc_pair(float* __restrict__ tbl,
                                         int* __restrict__ cnt,
                                         float4 v, int ca, int cb,
                                         int lane, int l31) {
    const int c = (lane >= 32) ? cb : ca;
    float* row = &tbl[c * DIM];
    atomicAdd(&row[l31     ], v.x);
    atomicAdd(&row[l31 + 32], v.y);
    atomicAdd(&row[l31 + 64], v.z);
    atomicAdd(&row[l31 + 96], v.w);
    if (l31 == 0) atomicAdd(&cnt[c], 1);   // lane 0 -> ca, lane 32 -> cb
}

// Squared-distance partial for one half-wave row against swizzled centers.
__device__ __forceinline__ float pair_dist2(const float* __restrict__ lcent,
                                            float4 v, int c, int l31) {
    const float* row = &lcent[c * DIM];
    float dx = v.x - row[l31     ];
    float dy = v.y - row[l31 + 32];
    float dz = v.z - row[l31 + 64];
    float dw = v.w - row[l31 + 96];
    return dx * dx + dy * dy + dz * dz + dw * dw;
}

// Fused kernel, normal launch, software grid barrier (proven in round 2).
// Phase 1: shared-table ds_add accumulation (no RMW chain) while holding
// 48/64 of each wave's pairs on-chip (32 in VGPRs, 16 in LDS).
// Phase 2: held pairs from regs/LDS (zero global input traffic); only the
// remaining 16/64 (33.5 MB) re-read from global.
__global__ __launch_bounds__(NTHR, 2)
void k_fused(const float4* __restrict__ in4, const int* __restrict__ tgt,
             float* __restrict__ gsums, int* __restrict__ gcounts,
             int* __restrict__ bar, float* __restrict__ out,
             int npair, float inv_n) {
    __shared__ __align__(16) float tbl[CD];              // 9728 B (swizzled)
    __shared__ __align__(16) float lcent[CD];            // 9728 B (swizzled)
    __shared__ int   cnt[NCLS];
    __shared__ float red[NTHR];                          // 2048 B
    __shared__ __align__(16) float4 holdl[WPB * NLP * 64]; // 131072 B

    const int tid  = threadIdx.x;
    const int w    = tid >> 6;
    const int lane = tid & 63;
    const int l31  = lane & 31;
    const int g    = blockIdx.x * WPB + w;   // global wave id, 0..2047

    for (int i = tid; i < CD; i += NTHR) tbl[i] = 0.0f;
    if (tid < NCLS) cnt[tid] = 0;
    __syncthreads();

    const bool exact = (npair == PPW * NWAVES);
    const int  lstop = exact ? (NRP + NLP) * NWAVES : 0;

    // ---- Phase 1a: register-held pairs (nt loads) ----
    float4 hold[NRP];                        // static indices only
    if (exact) {
        #pragma unroll
        for (int k = 0; k < NRP; k += 4) {
            const int p0 = (k + 0) * NWAVES + g;
            const int p1 = (k + 1) * NWAVES + g;
            const int p2 = (k + 2) * NWAVES + g;
            const int p3 = (k + 3) * NWAVES + g;
            float4 v0 = ntload4(&in4[(size_t)p0 * 64 + lane]);
            float4 v1 = ntload4(&in4[(size_t)p1 * 64 + lane]);
            float4 v2 = ntload4(&in4[(size_t)p2 * 64 + lane]);
            float4 v3 = ntload4(&in4[(size_t)p3 * 64 + lane]);
            int2 ab0 = *(const int2*)&tgt[2 * p0];
            int2 ab1 = *(const int2*)&tgt[2 * p1];
            int2 ab2 = *(const int2*)&tgt[2 * p2];
            int2 ab3 = *(const int2*)&tgt[2 * p3];
            hold[k + 0] = v0; hold[k + 1] = v1;
            hold[k + 2] = v2; hold[k + 3] = v3;
            acc_pair(tbl, cnt, v0, ab0.x, ab0.y, lane, l31);
            acc_pair(tbl, cnt, v1, ab1.x, ab1.y, lane, l31);
            acc_pair(tbl, cnt, v2, ab2.x, ab2.y, lane, l31);
            acc_pair(tbl, cnt, v3, ab3.x, ab3.y, lane, l31);
        }
        // ANCHOR: asm-produce every held value so the compiler cannot
        // rematerialize the loads in phase 2 (round-1 failure mode).
        #pragma unroll
        for (int k = 0; k < NRP; k++) {
            asm volatile("" : "+v"(hold[k].x), "+v"(hold[k].y),
                              "+v"(hold[k].z), "+v"(hold[k].w));
        }

        // ---- Phase 1c: LDS-held pairs (nt loads, stashed in LDS) ----
        float4* hbase = &holdl[(size_t)(w * NLP) * 64 + lane];
        #pragma unroll
        for (int k = 0; k < NLP; k += 4) {
            const int p0 = (NRP + k + 0) * NWAVES + g;
            const int p1 = (NRP + k + 1) * NWAVES + g;
            const int p2 = (NRP + k + 2) * NWAVES + g;
            const int p3 = (NRP + k + 3) * NWAVES + g;
            float4 v0 = ntload4(&in4[(size_t)p0 * 64 + lane]);
            float4 v1 = ntload4(&in4[(size_t)p1 * 64 + lane]);
            float4 v2 = ntload4(&in4[(size_t)p2 * 64 + lane]);
            float4 v3 = ntload4(&in4[(size_t)p3 * 64 + lane]);
            int2 ab0 = *(const int2*)&tgt[2 * p0];
            int2 ab1 = *(const int2*)&tgt[2 * p1];
            int2 ab2 = *(const int2*)&tgt[2 * p2];
            int2 ab3 = *(const int2*)&tgt[2 * p3];
            hbase[(k + 0) * 64] = v0;      // ds_write_b128, conflict-free
            hbase[(k + 1) * 64] = v1;
            hbase[(k + 2) * 64] = v2;
            hbase[(k + 3) * 64] = v3;
            acc_pair(tbl, cnt, v0, ab0.x, ab0.y, lane, l31);
            acc_pair(tbl, cnt, v1, ab1.x, ab1.y, lane, l31);
            acc_pair(tbl, cnt, v2, ab2.x, ab2.y, lane, l31);
            acc_pair(tbl, cnt, v3, ab3.x, ab3.y, lane, l31);
        }
    }

    // ---- Phase 1b: streamed pairs (cached loads; re-read hits L3) ----
    int p = lstop + g;
    for (; p + 3 * NWAVES < npair; p += 4 * NWAVES) {
        float4 v0 = in4[(size_t)(p             ) * 64 + lane];
        float4 v1 = in4[(size_t)(p +     NWAVES) * 64 + lane];
        float4 v2 = in4[(size_t)(p + 2 * NWAVES) * 64 + lane];
        float4 v3 = in4[(size_t)(p + 3 * NWAVES) * 64 + lane];
        int2 ab0 = *(const int2*)&tgt[2 * p];
        int2 ab1 = *(const int2*)&tgt[2 * (p + NWAVES)];
        int2 ab2 = *(const int2*)&tgt[2 * (p + 2 * NWAVES)];
        int2 ab3 = *(const int2*)&tgt[2 * (p + 3 * NWAVES)];
        acc_pair(tbl, cnt, v0, ab0.x, ab0.y, lane, l31);
        acc_pair(tbl, cnt, v1, ab1.x, ab1.y, lane, l31);
        acc_pair(tbl, cnt, v2, ab2.x, ab2.y, lane, l31);
        acc_pair(tbl, cnt, v3, ab3.x, ab3.y, lane, l31);
    }
    for (; p < npair; p += NWAVES) {
        float4 v = in4[(size_t)p * 64 + lane];
        int2 ab = *(const int2*)&tgt[2 * p];
        acc_pair(tbl, cnt, v, ab.x, ab.y, lane, l31);
    }
    __syncthreads();

    // ---- Block table -> device-scope atomics (swizzled layout preserved) ----
    for (int i = tid; i < CD; i += NTHR)
        unsafeAtomicAdd(&gsums[i], tbl[i]);
    if (tid < NCLS)
        atomicAdd(&gcounts[tid], cnt[tid]);

    // ---- Software grid barrier (device-scope; 1 block/CU co-residency) ----
    __syncthreads();
    if (tid == 0) {
        __hip_atomic_fetch_add(bar, 1, __ATOMIC_ACQ_REL,
                               __HIP_MEMORY_SCOPE_AGENT);
        while (__hip_atomic_load(bar, __ATOMIC_ACQUIRE,
                                 __HIP_MEMORY_SCOPE_AGENT) < NBLK) {
            __builtin_amdgcn_s_sleep(8);
        }
    }
    __syncthreads();

    // ---- Centers to LDS (agent-scope loads; swizzle preserved) ----
    for (int i = tid; i < CD; i += NTHR) {
        float s = __hip_atomic_load(&gsums[i], __ATOMIC_RELAXED,
                                    __HIP_MEMORY_SCOPE_AGENT);
        int   c = __hip_atomic_load(&gcounts[i >> 7], __ATOMIC_RELAXED,
                                    __HIP_MEMORY_SCOPE_AGENT);
        lcent[i] = s / (float)c;
    }
    __syncthreads();

    float acc = 0.0f;

    if (exact) {
        // ---- Phase 2a: register-held pairs (zero global input traffic) ----
        #pragma unroll
        for (int k = 0; k < NRP; k++) {
            const int pk = k * NWAVES + g;
            const int2 cc = *(const int2*)&tgt[2 * pk];
            const int c = (lane >= 32) ? cc.y : cc.x;
            float d = pair_dist2(lcent, hold[k], c, l31);
            d = reduce32_dpp(d);
            if (l31 == 31) acc += sqrtf(d);   // lanes 31 & 63
        }
        // ---- Phase 2c: LDS-held pairs ----
        const float4* hbase = &holdl[(size_t)(w * NLP) * 64 + lane];
        #pragma unroll
        for (int k = 0; k < NLP; k++) {
            const int pk = (NRP + k) * NWAVES + g;
            const int2 cc = *(const int2*)&tgt[2 * pk];
            const int c = (lane >= 32) ? cc.y : cc.x;
            float4 v = hbase[k * 64];         // ds_read_b128, conflict-free
            float d = pair_dist2(lcent, v, c, l31);
            d = reduce32_dpp(d);
            if (l31 == 31) acc += sqrtf(d);
        }
    }

    // ---- Phase 2b: streamed pairs re-read (33.5 MB, L3-resident) ----
    int q = lstop + g;
    for (; q + NWAVES < npair; q += 2 * NWAVES) {
        float4 va = in4[(size_t)q * 64 + lane];
        float4 vb = in4[(size_t)(q + NWAVES) * 64 + lane];
        int2 c2a = *(const int2*)&tgt[2 * q];
        int2 c2b = *(const int2*)&tgt[2 * (q + NWAVES)];
        int ca = (lane >= 32) ? c2a.y : c2a.x;
        int cb = (lane >= 32) ? c2b.y : c2b.x;
        float d0 = pair_dist2(lcent, va, ca, l31);
        float d1 = pair_dist2(lcent, vb, cb, l31);
        d0 = reduce32_dpp(d0);
        d1 = reduce32_dpp(d1);
        if (l31 == 31) acc += sqrtf(d0) + sqrtf(d1);
    }
    for (; q < npair; q += NWAVES) {
        float4 v = in4[(size_t)q * 64 + lane];
        int2 c2 = *(const int2*)&tgt[2 * q];
        int c = (lane >= 32) ? c2.y : c2.x;
        float d = pair_dist2(lcent, v, c, l31);
        d = reduce32_dpp(d);
        if (l31 == 31) acc += sqrtf(d);
    }

    red[tid] = acc;
    __syncthreads();
    for (int s = NTHR / 2; s > 0; s >>= 1) {
        if (tid < s) red[tid] += red[tid + s];
        __syncthreads();
    }
    if (tid == 0) unsafeAtomicAdd(out, red[0] * inv_n);
}

extern "C" void kernel_launch(void* const* d_in, const int* in_sizes, int n_in,
                              void* d_out, int out_size, void* d_ws, size_t ws_size,
                              hipStream_t stream) {
    const float* in  = (const float*)d_in[0];
    const int*   tgt = (const int*)d_in[1];
    const int n = in_sizes[0] / DIM;       // 262144

    float* gsums   = (float*)d_ws;             // [19][128] swizzled
    int*   gcounts = (int*)(gsums + CD);       // [19]
    int*   bar     = gcounts + NCLS;           // grid-barrier counter
    float* out     = (float*)d_out;

    (void)hipMemsetAsync(d_ws, 0, (CD + NCLS + 1) * sizeof(float), stream);
    (void)hipMemsetAsync(d_out, 0, sizeof(float), stream);

    const float4* in4 = (const float4*)in;
    k_fused<<<NBLK, NTHR, 0, stream>>>(in4, tgt, gsums, gcounts, bar,
                                       out, n / 2, 1.0f / (float)n);
}

// Round 6
// 358.676 us; speedup vs baseline: 1.0013x; 1.0013x over previous
//
#include <hip/hip_runtime.h>
#include <math.h>

#define NCLS 19
#define DIM  128
#define CD   (NCLS * DIM)   // 2432 floats
#define WPB  8              // waves per block (512 threads)
#define NBLK 256            // == CU count; 1 block/CU -> all co-resident
#define NTHR 512
#define NWAVES (NBLK * WPB) // 2048 waves grid-wide
#define NRP  32             // pairs held in registers per wave (128 VGPRs)
#define NLP  16             // pairs held in LDS per wave (16 KB/wave)
#define PPW  64             // pairs per wave in the exact-fit case

typedef float f32x4 __attribute__((ext_vector_type(4)));

// Nontemporal load for held data (never re-read from global) -> no L3 alloc.
__device__ __forceinline__ float4 ntload4(const float4* p) {
    f32x4 r = __builtin_nontemporal_load((const f32x4*)p);
    return make_float4(r.x, r.y, r.z, r.w);
}

// 32-lane-group sum via DPP on the VALU pipe. Valid in lanes 31 and 63.
template <int CTRL, int RMASK>
__device__ __forceinline__ float dpp_add(float x) {
    int t = __builtin_amdgcn_update_dpp(0, __builtin_bit_cast(int, x),
                                        CTRL, RMASK, 0xf, true);
    return x + __builtin_bit_cast(float, t);
}
__device__ __forceinline__ float reduce32_dpp(float x) {
    x = dpp_add<0x111, 0xf>(x);   // row_shr:1
    x = dpp_add<0x112, 0xf>(x);   // row_shr:2
    x = dpp_add<0x114, 0xf>(x);   // row_shr:4
    x = dpp_add<0x118, 0xf>(x);   // row_shr:8
    x = dpp_add<0x142, 0xa>(x);   // row_bcast15 -> lanes 31/63 hold 32-sums
    return x;
}

// Fire-and-forget accumulate into the block-shared SWIZZLED table.
// ROUND-5 FIX: plain atomicAdd(float*) compiles to a ds_cmpst CAS RETRY LOOP
// (no unsafe-fp-atomics) -> ~120cy serial LDS round-trips per add, which was
// the 86->209us regression (VALUBusy 15->5.4%, load rate 374 GB/s).
// unsafeAtomicAdd carries the unsafe-fp-atomics attribute -> native ds_add_f32.
// Table layout within a class row: dim d lives at word (d>>2) + (d&3)*32, so
// the 4 ds_add_f32 ops of a half-wave hit bank l31 (2 lanes/bank = free).
__device__ __forceinline__ void acc_pair(float* __restrict__ tbl,
                                         int* __restrict__ cnt,
                                         float4 v, int ca, int cb,
                                         int lane, int l31) {
    const int c = (lane >= 32) ? cb : ca;
    float* row = &tbl[c * DIM];
    unsafeAtomicAdd(&row[l31     ], v.x);
    unsafeAtomicAdd(&row[l31 + 32], v.y);
    unsafeAtomicAdd(&row[l31 + 64], v.z);
    unsafeAtomicAdd(&row[l31 + 96], v.w);
    if (l31 == 0) atomicAdd(&cnt[c], 1);   // int LDS atomic: native ds_add_u32
}

// Squared-distance partial for one half-wave row against swizzled centers.
__device__ __forceinline__ float pair_dist2(const float* __restrict__ lcent,
                                            float4 v, int c, int l31) {
    const float* row = &lcent[c * DIM];
    float dx = v.x - row[l31     ];
    float dy = v.y - row[l31 + 32];
    float dz = v.z - row[l31 + 64];
    float dw = v.w - row[l31 + 96];
    return dx * dx + dy * dy + dz * dz + dw * dw;
}

// Fused kernel, normal launch, software grid barrier (proven in round 2).
// Phase 1: shared-table ds_add accumulation (no RMW chain) while holding
// 48/64 of each wave's pairs on-chip (32 in VGPRs, 16 in LDS).
// Phase 2: held pairs from regs/LDS (zero global input traffic); only the
// remaining 16/64 (33.5 MB) re-read from global.
__global__ __launch_bounds__(NTHR, 2)
void k_fused(const float4* __restrict__ in4, const int* __restrict__ tgt,
             float* __restrict__ gsums, int* __restrict__ gcounts,
             int* __restrict__ bar, float* __restrict__ out,
             int npair, float inv_n) {
    __shared__ __align__(16) float tbl[CD];              // 9728 B (swizzled)
    __shared__ __align__(16) float lcent[CD];            // 9728 B (swizzled)
    __shared__ int   cnt[NCLS];
    __shared__ float red[NTHR];                          // 2048 B
    __shared__ __align__(16) float4 holdl[WPB * NLP * 64]; // 131072 B

    const int tid  = threadIdx.x;
    const int w    = tid >> 6;
    const int lane = tid & 63;
    const int l31  = lane & 31;
    const int g    = blockIdx.x * WPB + w;   // global wave id, 0..2047

    for (int i = tid; i < CD; i += NTHR) tbl[i] = 0.0f;
    if (tid < NCLS) cnt[tid] = 0;
    __syncthreads();

    const bool exact = (npair == PPW * NWAVES);
    const int  lstop = exact ? (NRP + NLP) * NWAVES : 0;

    // ---- Phase 1a: register-held pairs (nt loads) ----
    float4 hold[NRP];                        // static indices only
    if (exact) {
        #pragma unroll
        for (int k = 0; k < NRP; k += 4) {
            const int p0 = (k + 0) * NWAVES + g;
            const int p1 = (k + 1) * NWAVES + g;
            const int p2 = (k + 2) * NWAVES + g;
            const int p3 = (k + 3) * NWAVES + g;
            float4 v0 = ntload4(&in4[(size_t)p0 * 64 + lane]);
            float4 v1 = ntload4(&in4[(size_t)p1 * 64 + lane]);
            float4 v2 = ntload4(&in4[(size_t)p2 * 64 + lane]);
            float4 v3 = ntload4(&in4[(size_t)p3 * 64 + lane]);
            int2 ab0 = *(const int2*)&tgt[2 * p0];
            int2 ab1 = *(const int2*)&tgt[2 * p1];
            int2 ab2 = *(const int2*)&tgt[2 * p2];
            int2 ab3 = *(const int2*)&tgt[2 * p3];
            hold[k + 0] = v0; hold[k + 1] = v1;
            hold[k + 2] = v2; hold[k + 3] = v3;
            acc_pair(tbl, cnt, v0, ab0.x, ab0.y, lane, l31);
            acc_pair(tbl, cnt, v1, ab1.x, ab1.y, lane, l31);
            acc_pair(tbl, cnt, v2, ab2.x, ab2.y, lane, l31);
            acc_pair(tbl, cnt, v3, ab3.x, ab3.y, lane, l31);
        }
        // ANCHOR: asm-produce every held value so the compiler cannot
        // rematerialize the loads in phase 2 (round-1 failure mode).
        #pragma unroll
        for (int k = 0; k < NRP; k++) {
            asm volatile("" : "+v"(hold[k].x), "+v"(hold[k].y),
                              "+v"(hold[k].z), "+v"(hold[k].w));
        }

        // ---- Phase 1c: LDS-held pairs (nt loads, stashed in LDS) ----
        float4* hbase = &holdl[(size_t)(w * NLP) * 64 + lane];
        #pragma unroll
        for (int k = 0; k < NLP; k += 4) {
            const int p0 = (NRP + k + 0) * NWAVES + g;
            const int p1 = (NRP + k + 1) * NWAVES + g;
            const int p2 = (NRP + k + 2) * NWAVES + g;
            const int p3 = (NRP + k + 3) * NWAVES + g;
            float4 v0 = ntload4(&in4[(size_t)p0 * 64 + lane]);
            float4 v1 = ntload4(&in4[(size_t)p1 * 64 + lane]);
            float4 v2 = ntload4(&in4[(size_t)p2 * 64 + lane]);
            float4 v3 = ntload4(&in4[(size_t)p3 * 64 + lane]);
            int2 ab0 = *(const int2*)&tgt[2 * p0];
            int2 ab1 = *(const int2*)&tgt[2 * p1];
            int2 ab2 = *(const int2*)&tgt[2 * p2];
            int2 ab3 = *(const int2*)&tgt[2 * p3];
            hbase[(k + 0) * 64] = v0;      // ds_write_b128, conflict-free
            hbase[(k + 1) * 64] = v1;
            hbase[(k + 2) * 64] = v2;
            hbase[(k + 3) * 64] = v3;
            acc_pair(tbl, cnt, v0, ab0.x, ab0.y, lane, l31);
            acc_pair(tbl, cnt, v1, ab1.x, ab1.y, lane, l31);
            acc_pair(tbl, cnt, v2, ab2.x, ab2.y, lane, l31);
            acc_pair(tbl, cnt, v3, ab3.x, ab3.y, lane, l31);
        }
    }

    // ---- Phase 1b: streamed pairs (cached loads; re-read hits L3) ----
    int p = lstop + g;
    for (; p + 3 * NWAVES < npair; p += 4 * NWAVES) {
        float4 v0 = in4[(size_t)(p             ) * 64 + lane];
        float4 v1 = in4[(size_t)(p +     NWAVES) * 64 + lane];
        float4 v2 = in4[(size_t)(p + 2 * NWAVES) * 64 + lane];
        float4 v3 = in4[(size_t)(p + 3 * NWAVES) * 64 + lane];
        int2 ab0 = *(const int2*)&tgt[2 * p];
        int2 ab1 = *(const int2*)&tgt[2 * (p + NWAVES)];
        int2 ab2 = *(const int2*)&tgt[2 * (p + 2 * NWAVES)];
        int2 ab3 = *(const int2*)&tgt[2 * (p + 3 * NWAVES)];
        acc_pair(tbl, cnt, v0, ab0.x, ab0.y, lane, l31);
        acc_pair(tbl, cnt, v1, ab1.x, ab1.y, lane, l31);
        acc_pair(tbl, cnt, v2, ab2.x, ab2.y, lane, l31);
        acc_pair(tbl, cnt, v3, ab3.x, ab3.y, lane, l31);
    }
    for (; p < npair; p += NWAVES) {
        float4 v = in4[(size_t)p * 64 + lane];
        int2 ab = *(const int2*)&tgt[2 * p];
        acc_pair(tbl, cnt, v, ab.x, ab.y, lane, l31);
    }
    __syncthreads();

    // ---- Block table -> device-scope atomics (swizzled layout preserved) ----
    for (int i = tid; i < CD; i += NTHR)
        unsafeAtomicAdd(&gsums[i], tbl[i]);
    if (tid < NCLS)
        atomicAdd(&gcounts[tid], cnt[tid]);

    // ---- Software grid barrier (device-scope; 1 block/CU co-residency) ----
    __syncthreads();
    if (tid == 0) {
        __hip_atomic_fetch_add(bar, 1, __ATOMIC_ACQ_REL,
                               __HIP_MEMORY_SCOPE_AGENT);
        while (__hip_atomic_load(bar, __ATOMIC_ACQUIRE,
                                 __HIP_MEMORY_SCOPE_AGENT) < NBLK) {
            __builtin_amdgcn_s_sleep(8);
        }
    }
    __syncthreads();

    // ---- Centers to LDS (agent-scope loads; swizzle preserved) ----
    for (int i = tid; i < CD; i += NTHR) {
        float s = __hip_atomic_load(&gsums[i], __ATOMIC_RELAXED,
                                    __HIP_MEMORY_SCOPE_AGENT);
        int   c = __hip_atomic_load(&gcounts[i >> 7], __ATOMIC_RELAXED,
                                    __HIP_MEMORY_SCOPE_AGENT);
        lcent[i] = s / (float)c;
    }
    __syncthreads();

    float acc = 0.0f;

    if (exact) {
        // ---- Phase 2a: register-held pairs (zero global input traffic) ----
        #pragma unroll
        for (int k = 0; k < NRP; k++) {
            const int pk = k * NWAVES + g;
            const int2 cc = *(const int2*)&tgt[2 * pk];
            const int c = (lane >= 32) ? cc.y : cc.x;
            float d = pair_dist2(lcent, hold[k], c, l31);
            d = reduce32_dpp(d);
            if (l31 == 31) acc += sqrtf(d);   // lanes 31 & 63
        }
        // ---- Phase 2c: LDS-held pairs ----
        const float4* hbase = &holdl[(size_t)(w * NLP) * 64 + lane];
        #pragma unroll
        for (int k = 0; k < NLP; k++) {
            const int pk = (NRP + k) * NWAVES + g;
            const int2 cc = *(const int2*)&tgt[2 * pk];
            const int c = (lane >= 32) ? cc.y : cc.x;
            float4 v = hbase[k * 64];         // ds_read_b128, conflict-free
            float d = pair_dist2(lcent, v, c, l31);
            d = reduce32_dpp(d);
            if (l31 == 31) acc += sqrtf(d);
        }
    }

    // ---- Phase 2b: streamed pairs re-read (33.5 MB, L3-resident) ----
    int q = lstop + g;
    for (; q + NWAVES < npair; q += 2 * NWAVES) {
        float4 va = in4[(size_t)q * 64 + lane];
        float4 vb = in4[(size_t)(q + NWAVES) * 64 + lane];
        int2 c2a = *(const int2*)&tgt[2 * q];
        int2 c2b = *(const int2*)&tgt[2 * (q + NWAVES)];
        int ca = (lane >= 32) ? c2a.y : c2a.x;
        int cb = (lane >= 32) ? c2b.y : c2b.x;
        float d0 = pair_dist2(lcent, va, ca, l31);
        float d1 = pair_dist2(lcent, vb, cb, l31);
        d0 = reduce32_dpp(d0);
        d1 = reduce32_dpp(d1);
        if (l31 == 31) acc += sqrtf(d0) + sqrtf(d1);
    }
    for (; q < npair; q += NWAVES) {
        float4 v = in4[(size_t)q * 64 + lane];
        int2 c2 = *(const int2*)&tgt[2 * q];
        int c = (lane >= 32) ? c2.y : c2.x;
        float d = pair_dist2(lcent, v, c, l31);
        d = reduce32_dpp(d);
        if (l31 == 31) acc += sqrtf(d);
    }

    red[tid] = acc;
    __syncthreads();
    for (int s = NTHR / 2; s > 0; s >>= 1) {
        if (tid < s) red[tid] += red[tid + s];
        __syncthreads();
    }
    if (tid == 0) unsafeAtomicAdd(out, red[0] * inv_n);
}

extern "C" void kernel_launch(void* const* d_in, const int* in_sizes, int n_in,
                              void* d_out, int out_size, void* d_ws, size_t ws_size,
                              hipStream_t stream) {
    const float* in  = (const float*)d_in[0];
    const int*   tgt = (const int*)d_in[1];
    const int n = in_sizes[0] / DIM;       // 262144

    float* gsums   = (float*)d_ws;             // [19][128] swizzled
    int*   gcounts = (int*)(gsums + CD);       // [19]
    int*   bar     = gcounts + NCLS;           // grid-barrier counter
    float* out     = (float*)d_out;

    (void)hipMemsetAsync(d_ws, 0, (CD + NCLS + 1) * sizeof(float), stream);
    (void)hipMemsetAsync(d_out, 0, sizeof(float), stream);

    const float4* in4 = (const float4*)in;
    k_fused<<<NBLK, NTHR, 0, stream>>>(in4, tgt, gsums, gcounts, bar,
                                       out, n / 2, 1.0f / (float)n);
}

// Round 8
// 230.266 us; speedup vs baseline: 1.5596x; 1.5577x over previous
//
#include <hip/hip_runtime.h>
#include <math.h>

#define NCLS 19
#define DIM  128
#define CD   (NCLS * DIM)   // 2432 floats
#define WPB  8              // waves per block (512 threads)
#define NBLK 256            // == CU count; 1 block/CU -> all co-resident
#define NTHR 512
#define NWAVES (NBLK * WPB) // 2048 waves grid-wide
#define NRP  32             // pairs held in registers per wave (128 VGPRs)
#define NLP  8              // pairs held in LDS per wave (8 KB/wave)
#define PPW  64             // pairs per wave in the exact-fit case

typedef float f32x4 __attribute__((ext_vector_type(4)));

// Nontemporal load for held data (never re-read from global) -> no L3 alloc.
__device__ __forceinline__ float4 ntload4(const float4* p) {
    f32x4 r = __builtin_nontemporal_load((const f32x4*)p);
    return make_float4(r.x, r.y, r.z, r.w);
}

// 32-lane-group sum via DPP on the VALU pipe. Valid in lanes 31 and 63.
template <int CTRL, int RMASK>
__device__ __forceinline__ float dpp_add(float x) {
    int t = __builtin_amdgcn_update_dpp(0, __builtin_bit_cast(int, x),
                                        CTRL, RMASK, 0xf, true);
    return x + __builtin_bit_cast(float, t);
}
__device__ __forceinline__ float reduce32_dpp(float x) {
    x = dpp_add<0x111, 0xf>(x);   // row_shr:1
    x = dpp_add<0x112, 0xf>(x);   // row_shr:2
    x = dpp_add<0x114, 0xf>(x);   // row_shr:4
    x = dpp_add<0x118, 0xf>(x);   // row_shr:8
    x = dpp_add<0x142, 0xa>(x);   // row_bcast15 -> lanes 31/63 hold 32-sums
    return x;
}

// ROUND-7: revert to the PROVEN private-table RMW accumulator (round-2,
// 86us e2e). Rounds 5/6 proved the shared-table ds-atomic design is
// latency-serialized at 2 waves/SIMD (207us, VALUBusy 5.4%, replay-warm
// equally slow) regardless of atomicAdd flavor.
__device__ __forceinline__ void proc_pair(float* __restrict__ tbl,
                                          int* __restrict__ cnt,
                                          float4 v, int ca, int cb,
                                          int lane, int l31) {
    if (ca == cb) {
        v.x += __shfl_xor(v.x, 32, 64);
        v.y += __shfl_xor(v.y, 32, 64);
        v.z += __shfl_xor(v.z, 32, 64);
        v.w += __shfl_xor(v.w, 32, 64);
        float4* q = (float4*)&tbl[ca * DIM + l31 * 4];
        float4 a = *q;
        a.x += v.x; a.y += v.y; a.z += v.z; a.w += v.w;
        *q = a;                       // both halves write identical values
        if (lane == 0) cnt[ca] += 2;
    } else {
        int c = (lane >= 32) ? cb : ca;
        float4* q = (float4*)&tbl[c * DIM + l31 * 4];
        float4 a = *q;
        a.x += v.x; a.y += v.y; a.z += v.z; a.w += v.w;
        *q = a;                       // halves hit different class rows
        if (lane == 0)  cnt[ca]++;
        if (lane == 32) cnt[cb]++;
    }
}

// Fused kernel, normal launch, software grid barrier (proven round 2).
// Phase 1: private-table RMW accumulation while holding 40/64 of each
// wave's pairs on-chip (32 in VGPRs, 8 in LDS).
// Phase 2: held pairs from regs/LDS; only 24/64 (50 MB) re-read.
// lcent ALIASES the dead private-table LDS after the grid barrier.
__global__ __launch_bounds__(NTHR, 2)
void k_fused(const float4* __restrict__ in4, const int* __restrict__ tgt,
             float* __restrict__ gsums, int* __restrict__ gcounts,
             int* __restrict__ bar, float* __restrict__ out,
             int npair, float inv_n) {
    __shared__ __align__(16) float ls[WPB * CD];           // 77824 B
    __shared__ int   lcnt[WPB * NCLS];                     // 608 B
    __shared__ float red[NTHR];                            // 2048 B
    __shared__ __align__(16) float4 holdl[WPB * NLP * 64]; // 65536 B

    const int tid  = threadIdx.x;
    const int w    = tid >> 6;
    const int lane = tid & 63;
    const int l31  = lane & 31;
    float* tbl = &ls[w * CD];
    int*   cnt = &lcnt[w * NCLS];
    const int g = blockIdx.x * WPB + w;      // global wave id, 0..2047

    for (int i = tid; i < WPB * CD; i += NTHR) ls[i] = 0.0f;
    for (int i = tid; i < WPB * NCLS; i += NTHR) lcnt[i] = 0;
    __syncthreads();

    const bool exact = (npair == PPW * NWAVES);
    const int  lstop = exact ? (NRP + NLP) * NWAVES : 0;

    // ---- Phase 1a: register-held pairs (nt loads) ----
    float4 hold[NRP];                        // static indices only
    if (exact) {
        #pragma unroll
        for (int k = 0; k < NRP; k += 4) {
            const int p0 = (k + 0) * NWAVES + g;
            const int p1 = (k + 1) * NWAVES + g;
            const int p2 = (k + 2) * NWAVES + g;
            const int p3 = (k + 3) * NWAVES + g;
            float4 v0 = ntload4(&in4[(size_t)p0 * 64 + lane]);
            float4 v1 = ntload4(&in4[(size_t)p1 * 64 + lane]);
            float4 v2 = ntload4(&in4[(size_t)p2 * 64 + lane]);
            float4 v3 = ntload4(&in4[(size_t)p3 * 64 + lane]);
            int2 ab0 = *(const int2*)&tgt[2 * p0];
            int2 ab1 = *(const int2*)&tgt[2 * p1];
            int2 ab2 = *(const int2*)&tgt[2 * p2];
            int2 ab3 = *(const int2*)&tgt[2 * p3];
            hold[k + 0] = v0; hold[k + 1] = v1;
            hold[k + 2] = v2; hold[k + 3] = v3;
            proc_pair(tbl, cnt, v0, ab0.x, ab0.y, lane, l31);
            proc_pair(tbl, cnt, v1, ab1.x, ab1.y, lane, l31);
            proc_pair(tbl, cnt, v2, ab2.x, ab2.y, lane, l31);
            proc_pair(tbl, cnt, v3, ab3.x, ab3.y, lane, l31);
        }
        // ANCHOR: asm-produce every held value so the compiler cannot
        // rematerialize the loads in phase 2 (round-1 failure mode).
        #pragma unroll
        for (int k = 0; k < NRP; k++) {
            asm volatile("" : "+v"(hold[k].x), "+v"(hold[k].y),
                              "+v"(hold[k].z), "+v"(hold[k].w));
        }

        // ---- Phase 1c: LDS-held pairs (nt loads, stashed in LDS) ----
        float4* hbase = &holdl[(size_t)(w * NLP) * 64 + lane];
        #pragma unroll
        for (int k = 0; k < NLP; k += 4) {
            const int p0 = (NRP + k + 0) * NWAVES + g;
            const int p1 = (NRP + k + 1) * NWAVES + g;
            const int p2 = (NRP + k + 2) * NWAVES + g;
            const int p3 = (NRP + k + 3) * NWAVES + g;
            float4 v0 = ntload4(&in4[(size_t)p0 * 64 + lane]);
            float4 v1 = ntload4(&in4[(size_t)p1 * 64 + lane]);
            float4 v2 = ntload4(&in4[(size_t)p2 * 64 + lane]);
            float4 v3 = ntload4(&in4[(size_t)p3 * 64 + lane]);
            int2 ab0 = *(const int2*)&tgt[2 * p0];
            int2 ab1 = *(const int2*)&tgt[2 * p1];
            int2 ab2 = *(const int2*)&tgt[2 * p2];
            int2 ab3 = *(const int2*)&tgt[2 * p3];
            hbase[(k + 0) * 64] = v0;      // ds_write_b128, conflict-free
            hbase[(k + 1) * 64] = v1;
            hbase[(k + 2) * 64] = v2;
            hbase[(k + 3) * 64] = v3;
            proc_pair(tbl, cnt, v0, ab0.x, ab0.y, lane, l31);
            proc_pair(tbl, cnt, v1, ab1.x, ab1.y, lane, l31);
            proc_pair(tbl, cnt, v2, ab2.x, ab2.y, lane, l31);
            proc_pair(tbl, cnt, v3, ab3.x, ab3.y, lane, l31);
        }
    }

    // ---- Phase 1b: streamed pairs (cached loads; re-read hits L3) ----
    int p = lstop + g;
    for (; p + 3 * NWAVES < npair; p += 4 * NWAVES) {
        float4 v0 = in4[(size_t)(p             ) * 64 + lane];
        float4 v1 = in4[(size_t)(p +     NWAVES) * 64 + lane];
        float4 v2 = in4[(size_t)(p + 2 * NWAVES) * 64 + lane];
        float4 v3 = in4[(size_t)(p + 3 * NWAVES) * 64 + lane];
        int2 ab0 = *(const int2*)&tgt[2 * p];
        int2 ab1 = *(const int2*)&tgt[2 * (p + NWAVES)];
        int2 ab2 = *(const int2*)&tgt[2 * (p + 2 * NWAVES)];
        int2 ab3 = *(const int2*)&tgt[2 * (p + 3 * NWAVES)];
        proc_pair(tbl, cnt, v0, ab0.x, ab0.y, lane, l31);
        proc_pair(tbl, cnt, v1, ab1.x, ab1.y, lane, l31);
        proc_pair(tbl, cnt, v2, ab2.x, ab2.y, lane, l31);
        proc_pair(tbl, cnt, v3, ab3.x, ab3.y, lane, l31);
    }
    for (; p < npair; p += NWAVES) {
        float4 v = in4[(size_t)p * 64 + lane];
        int2 ab = *(const int2*)&tgt[2 * p];
        proc_pair(tbl, cnt, v, ab.x, ab.y, lane, l31);
    }
    __syncthreads();

    // ---- Cross-wave reduce -> device-scope atomics ----
    for (int i = tid; i < CD; i += NTHR) {
        float s = 0.0f;
        #pragma unroll
        for (int ww = 0; ww < WPB; ww++) s += ls[ww * CD + i];
        unsafeAtomicAdd(&gsums[i], s);
    }
    if (tid < NCLS) {
        int s = 0;
        #pragma unroll
        for (int ww = 0; ww < WPB; ww++) s += lcnt[ww * NCLS + tid];
        atomicAdd(&gcounts[tid], s);
    }

    // ---- Software grid barrier (device-scope; 1 block/CU co-residency) ----
    __syncthreads();
    if (tid == 0) {
        __hip_atomic_fetch_add(bar, 1, __ATOMIC_ACQ_REL,
                               __HIP_MEMORY_SCOPE_AGENT);
        while (__hip_atomic_load(bar, __ATOMIC_ACQUIRE,
                                 __HIP_MEMORY_SCOPE_AGENT) < NBLK) {
            __builtin_amdgcn_s_sleep(8);
        }
    }
    __syncthreads();

    // ---- Centers to LDS, ALIASING the dead private tables ----
    // Safe: all flush reads of ls happened before the pre-spin
    // __syncthreads; these writes happen after the post-spin one.
    float* lcent = ls;
    for (int i = tid; i < CD; i += NTHR) {
        float s = __hip_atomic_load(&gsums[i], __ATOMIC_RELAXED,
                                    __HIP_MEMORY_SCOPE_AGENT);
        int   c = __hip_atomic_load(&gcounts[i >> 7], __ATOMIC_RELAXED,
                                    __HIP_MEMORY_SCOPE_AGENT);
        lcent[i] = s / (float)c;
    }
    __syncthreads();

    float acc = 0.0f;

    if (exact) {
        // ---- Phase 2a: register-held pairs (zero global input traffic) ----
        #pragma unroll
        for (int k = 0; k < NRP; k++) {
            const int pk = k * NWAVES + g;
            const int2 cc = *(const int2*)&tgt[2 * pk];
            const int c = (lane >= 32) ? cc.y : cc.x;
            const float4 e = *(const float4*)&lcent[c * DIM + l31 * 4];
            const float4 v = hold[k];
            float dx = v.x - e.x, dy = v.y - e.y;
            float dz = v.z - e.z, dw = v.w - e.w;
            float d = dx * dx + dy * dy + dz * dz + dw * dw;
            d = reduce32_dpp(d);
            if (l31 == 31) acc += sqrtf(d);   // lanes 31 & 63
        }
        // ---- Phase 2c: LDS-held pairs ----
        const float4* hbase = &holdl[(size_t)(w * NLP) * 64 + lane];
        #pragma unroll
        for (int k = 0; k < NLP; k++) {
            const int pk = (NRP + k) * NWAVES + g;
            const int2 cc = *(const int2*)&tgt[2 * pk];
            const int c = (lane >= 32) ? cc.y : cc.x;
            float4 v = hbase[k * 64];         // ds_read_b128, conflict-free
            const float4 e = *(const float4*)&lcent[c * DIM + l31 * 4];
            float dx = v.x - e.x, dy = v.y - e.y;
            float dz = v.z - e.z, dw = v.w - e.w;
            float d = dx * dx + dy * dy + dz * dz + dw * dw;
            d = reduce32_dpp(d);
            if (l31 == 31) acc += sqrtf(d);
        }
    }

    // ---- Phase 2b: streamed pairs re-read (50 MB, mostly L3-resident) ----
    int q = lstop + g;
    for (; q + NWAVES < npair; q += 2 * NWAVES) {
        float4 va = in4[(size_t)q * 64 + lane];
        float4 vb = in4[(size_t)(q + NWAVES) * 64 + lane];
        int2 c2a = *(const int2*)&tgt[2 * q];
        int2 c2b = *(const int2*)&tgt[2 * (q + NWAVES)];
        int ca = (lane >= 32) ? c2a.y : c2a.x;
        int cb = (lane >= 32) ? c2b.y : c2b.x;
        const float4 ea = *(const float4*)&lcent[ca * DIM + l31 * 4];
        const float4 eb = *(const float4*)&lcent[cb * DIM + l31 * 4];
        float dx, dy, dz, dw;
        dx = va.x - ea.x; dy = va.y - ea.y; dz = va.z - ea.z; dw = va.w - ea.w;
        float d0 = dx * dx + dy * dy + dz * dz + dw * dw;
        dx = vb.x - eb.x; dy = vb.y - eb.y; dz = vb.z - eb.z; dw = vb.w - eb.w;
        float d1 = dx * dx + dy * dy + dz * dz + dw * dw;
        d0 = reduce32_dpp(d0);
        d1 = reduce32_dpp(d1);
        if (l31 == 31) acc += sqrtf(d0) + sqrtf(d1);
    }
    for (; q < npair; q += NWAVES) {
        float4 v = in4[(size_t)q * 64 + lane];
        int2 c2 = *(const int2*)&tgt[2 * q];
        int c = (lane >= 32) ? c2.y : c2.x;
        const float4 e = *(const float4*)&lcent[c * DIM + l31 * 4];
        float dx = v.x - e.x, dy = v.y - e.y, dz = v.z - e.z, dw = v.w - e.w;
        float d = dx * dx + dy * dy + dz * dz + dw * dw;
        d = reduce32_dpp(d);
        if (l31 == 31) acc += sqrtf(d);
    }

    red[tid] = acc;
    __syncthreads();
    for (int s = NTHR / 2; s > 0; s >>= 1) {
        if (tid < s) red[tid] += red[tid + s];
        __syncthreads();
    }
    if (tid == 0) unsafeAtomicAdd(out, red[0] * inv_n);
}

extern "C" void kernel_launch(void* const* d_in, const int* in_sizes, int n_in,
                              void* d_out, int out_size, void* d_ws, size_t ws_size,
                              hipStream_t stream) {
    const float* in  = (const float*)d_in[0];
    const int*   tgt = (const int*)d_in[1];
    const int n = in_sizes[0] / DIM;       // 262144

    float* gsums   = (float*)d_ws;             // [19][128]
    int*   gcounts = (int*)(gsums + CD);       // [19]
    int*   bar     = gcounts + NCLS;           // grid-barrier counter
    float* out     = (float*)d_out;

    (void)hipMemsetAsync(d_ws, 0, (CD + NCLS + 1) * sizeof(float), stream);
    (void)hipMemsetAsync(d_out, 0, sizeof(float), stream);

    const float4* in4 = (const float4*)in;
    k_fused<<<NBLK, NTHR, 0, stream>>>(in4, tgt, gsums, gcounts, bar,
                                       out, n / 2, 1.0f / (float)n);
}